// Round 1
// baseline (186.625 us; speedup 1.0000x reference)
//
#include <hip/hip_runtime.h>

typedef unsigned short u16;
typedef __attribute__((ext_vector_type(8))) short short8;
typedef __attribute__((ext_vector_type(4))) float f32x4;
typedef __attribute__((ext_vector_type(4))) unsigned short u16x4;

#define MFMA16(a,b,c) __builtin_amdgcn_mfma_f32_16x16x32_bf16((a),(b),(c),0,0,0)

__device__ __forceinline__ u16 f2bf(float x){
  union { float f; unsigned u; } un; un.f = x;
  unsigned r = un.u + 0x7fffu + ((un.u >> 16) & 1u);
  return (u16)(r >> 16);
}

// ---------------- f32 -> bf16 convert (activations) ----------------
__global__ __launch_bounds__(256) void cvt_x(const float* __restrict__ in, u16* __restrict__ out){
  int i = (blockIdx.x * 256 + threadIdx.x) * 4;
  f32x4 v = *(const f32x4*)(in + i);
  u16x4 r = { f2bf(v[0]), f2bf(v[1]), f2bf(v[2]), f2bf(v[3]) };
  *(u16x4*)(out + i) = r;
}

// ---------------- weight transpose+convert: out[n][k] = in[k][n], 512x512 ----------------
__global__ __launch_bounds__(256) void wtrans(const float* __restrict__ W0, const float* __restrict__ W1,
                                              const float* __restrict__ W2, const float* __restrict__ W3,
                                              u16* __restrict__ out){
  __shared__ float tile[32][33];
  const float* src = (blockIdx.z == 0) ? W0 : (blockIdx.z == 1) ? W1 : (blockIdx.z == 2) ? W2 : W3;
  u16* dst = out + (size_t)blockIdx.z * 262144;
  int k0 = blockIdx.x * 32, n0 = blockIdx.y * 32;
  int tx = threadIdx.x, ty = threadIdx.y;
  #pragma unroll
  for (int i = 0; i < 4; ++i)
    tile[ty + 8*i][tx] = src[(size_t)(k0 + ty + 8*i)*512 + n0 + tx];
  __syncthreads();
  #pragma unroll
  for (int i = 0; i < 4; ++i)
    dst[(size_t)(n0 + ty + 8*i)*512 + k0 + tx] = f2bf(tile[tx][ty + 8*i]);
}

// ---------------- GEMM: C[M,512] = A[M,512](bf16) * BT[512,512]^T(bf16) + bias ----------------
// mode 0: bf16 out remapped to [B,H,S,D] (row=b*8192+s, col=h*64+d)
// mode 1: f32 out, plain row-major [M,512]
__global__ __launch_bounds__(256) void gemm512(const u16* __restrict__ A, const u16* __restrict__ BT,
                                               const float* __restrict__ bias,
                                               u16* __restrict__ outb, float* __restrict__ outf, int mode){
  __shared__ u16 lA[128*32];
  __shared__ u16 lB[128*32];
  const int tid = threadIdx.x, lane = tid & 63, w = tid >> 6;
  const int g = lane >> 4, c = lane & 15;
  const int bm = blockIdx.x, bn = blockIdx.y;
  const int wm = (w >> 1) * 64, wn = (w & 1) * 64;
  f32x4 acc[4][4];
  #pragma unroll
  for (int mi = 0; mi < 4; ++mi)
    #pragma unroll
    for (int ni = 0; ni < 4; ++ni){ f32x4 z = {0.f,0.f,0.f,0.f}; acc[mi][ni] = z; }

  for (int kt = 0; kt < 16; ++kt){
    #pragma unroll
    for (int j = 0; j < 2; ++j){
      int lrow = 32*w + 16*j;
      const u16* ga = A  + (size_t)(bm*128 + lrow + (lane >> 2))*512 + kt*32 + (lane & 3)*8;
      __builtin_amdgcn_global_load_lds((const __attribute__((address_space(1))) void*)ga,
          (__attribute__((address_space(3))) void*)&lA[lrow*32], 16, 0, 0);
      const u16* gb = BT + (size_t)(bn*128 + lrow + (lane >> 2))*512 + kt*32 + (lane & 3)*8;
      __builtin_amdgcn_global_load_lds((const __attribute__((address_space(1))) void*)gb,
          (__attribute__((address_space(3))) void*)&lB[lrow*32], 16, 0, 0);
    }
    __syncthreads();
    short8 af[4], bf[4];
    #pragma unroll
    for (int i = 0; i < 4; ++i){
      af[i] = *(const short8*)&lA[(wm + 16*i + c)*32 + g*8];
      bf[i] = *(const short8*)&lB[(wn + 16*i + c)*32 + g*8];
    }
    #pragma unroll
    for (int mi = 0; mi < 4; ++mi)
      #pragma unroll
      for (int ni = 0; ni < 4; ++ni)
        acc[mi][ni] = MFMA16(af[mi], bf[ni], acc[mi][ni]);
    __syncthreads();
  }

  #pragma unroll
  for (int mi = 0; mi < 4; ++mi){
    #pragma unroll
    for (int ni = 0; ni < 4; ++ni){
      int col = bn*128 + wn + 16*ni + c;
      float bv = bias[col];
      #pragma unroll
      for (int r = 0; r < 4; ++r){
        int row = bm*128 + wm + 16*mi + 4*g + r;
        float v = acc[mi][ni][r] + bv;
        if (mode == 0){
          int bb = row >> 13, s = row & 8191, hh = col >> 6, d = col & 63;
          outb[((size_t)(bb*8 + hh)*8192 + s)*64 + d] = f2bf(v);
        } else {
          outf[(size_t)row*512 + col] = v;
        }
      }
    }
  }
}

// ---------------- banded flash attention ----------------
// grid (nb=64, H=8, B=2), 256 threads; q,k,v in [B,H,S,D] bf16; o out [B,S,H*D] bf16
__global__ __launch_bounds__(256) void attn64(const u16* __restrict__ Qg, const u16* __restrict__ Kg,
                                              const u16* __restrict__ Vg, u16* __restrict__ Og){
  __shared__ u16 lK[128*64];     // 16 KB, XOR-swizzled rows
  __shared__ u16 lV[64*128];     // 16 KB, V^T with (d^(d>>3)) swizzle
  __shared__ u16 lP[128*128];    // 32 KB, per-wave 32-row slices
  const int tid = threadIdx.x, lane = tid & 63, w = tid >> 6;
  const int g = lane >> 4, c = lane & 15;
  const int n = blockIdx.x, h = blockIdx.y, b = blockIdx.z;
  const size_t base = ((size_t)(b*8 + h)) * (8192*64);

  // Q fragments (A-operand), held for the whole block
  short8 qf[2][2];
  #pragma unroll
  for (int mi = 0; mi < 2; ++mi)
    #pragma unroll
    for (int dt = 0; dt < 2; ++dt){
      int row = n*128 + 32*w + 16*mi + c;
      qf[mi][dt] = *(const short8*)(Qg + base + (size_t)row*64 + dt*32 + g*8);
    }

  float m_s[2][4], l_s[2][4];
  f32x4 oacc[2][4];
  #pragma unroll
  for (int mi = 0; mi < 2; ++mi)
    #pragma unroll
    for (int r = 0; r < 4; ++r){ m_s[mi][r] = -1e30f; l_s[mi][r] = 0.f; }
  #pragma unroll
  for (int mi = 0; mi < 2; ++mi)
    #pragma unroll
    for (int dn = 0; dn < 4; ++dn){ f32x4 z = {0.f,0.f,0.f,0.f}; oacc[mi][dn] = z; }

  const int lo = (n == 0) ? 1 : 0;
  const int hi = (n == 63) ? 1 : 2;
  for (int kb = lo; kb <= hi; ++kb){
    // ---- stage K (row-swizzled) and V^T ----
    {
      int r0 = tid >> 3, cc = tid & 7;
      #pragma unroll
      for (int p = 0; p < 4; ++p){
        int r = p*32 + r0;
        size_t grow = base + (size_t)(n*128 + (kb-1)*128 + r) * 64 + cc*8;
        short8 k8 = *(const short8*)(Kg + grow);
        int byt = (r*128 + cc*16) ^ ((r & 7) << 4);
        *(short8*)((char*)lK + byt) = k8;
        short8 v8 = *(const short8*)(Vg + grow);
        #pragma unroll
        for (int jj = 0; jj < 8; ++jj){
          int dd = cc*8 + jj;
          int byt2 = (dd*256 + r*2) ^ ((((dd >> 3) ^ dd) & 7) << 4);
          *(u16*)((char*)lV + byt2) = (u16)v8[jj];
        }
      }
    }
    __syncthreads();

    // ---- scores S = Q K^T ----
    f32x4 sc[2][8];
    #pragma unroll
    for (int mi = 0; mi < 2; ++mi)
      #pragma unroll
      for (int nt = 0; nt < 8; ++nt){ f32x4 z = {0.f,0.f,0.f,0.f}; sc[mi][nt] = z; }
    #pragma unroll
    for (int nt = 0; nt < 8; ++nt){
      int kp = nt*16 + c;
      #pragma unroll
      for (int dt = 0; dt < 2; ++dt){
        int byt = (kp*128 + dt*64 + g*16) ^ ((kp & 7) << 4);
        short8 kf = *(const short8*)((char*)lK + byt);
        sc[0][nt] = MFMA16(qf[0][dt], kf, sc[0][nt]);
        sc[1][nt] = MFMA16(qf[1][dt], kf, sc[1][nt]);
      }
    }

    // ---- band mask + scale + online softmax; write P (bf16) to LDS ----
    #pragma unroll
    for (int mi = 0; mi < 2; ++mi){
      float mnew[4];
      #pragma unroll
      for (int r = 0; r < 4; ++r) mnew[r] = -1e30f;
      #pragma unroll
      for (int nt = 0; nt < 8; ++nt){
        int kpw = kb*128 + nt*16 + c;
        #pragma unroll
        for (int r = 0; r < 4; ++r){
          int qp = 32*w + 16*mi + 4*g + r;
          float s = (kpw >= qp && kpw <= qp + 255) ? sc[mi][nt][r] * 0.125f : -1e30f;
          sc[mi][nt][r] = s;
          mnew[r] = fmaxf(mnew[r], s);
        }
      }
      #pragma unroll
      for (int r = 0; r < 4; ++r){
        float v = mnew[r];
        v = fmaxf(v, __shfl_xor(v, 1));
        v = fmaxf(v, __shfl_xor(v, 2));
        v = fmaxf(v, __shfl_xor(v, 4));
        v = fmaxf(v, __shfl_xor(v, 8));
        float mn = fmaxf(m_s[mi][r], v);
        float sc0 = __builtin_amdgcn_exp2f((m_s[mi][r] - mn) * 1.44269504f);
        m_s[mi][r] = mn;
        l_s[mi][r] *= sc0;
        #pragma unroll
        for (int dn = 0; dn < 4; ++dn) oacc[mi][dn][r] *= sc0;
        mnew[r] = mn;
      }
      float rsum[4] = {0.f, 0.f, 0.f, 0.f};
      #pragma unroll
      for (int nt = 0; nt < 8; ++nt){
        int col = nt*16 + c;
        #pragma unroll
        for (int r = 0; r < 4; ++r){
          float p = __builtin_amdgcn_exp2f((sc[mi][nt][r] - mnew[r]) * 1.44269504f);
          rsum[r] += p;
          int row = 32*w + 16*mi + 4*g + r;
          int byt = (row*256 + col*2) ^ ((row & 7) << 4);
          *(u16*)((char*)lP + byt) = f2bf(p);
        }
      }
      #pragma unroll
      for (int r = 0; r < 4; ++r){
        float v = rsum[r];
        v += __shfl_xor(v, 1);
        v += __shfl_xor(v, 2);
        v += __shfl_xor(v, 4);
        v += __shfl_xor(v, 8);
        l_s[mi][r] += v;
      }
    }
    __syncthreads();

    // ---- O += P V ----
    #pragma unroll
    for (int kt = 0; kt < 4; ++kt){
      short8 pa[2], vb[4];
      #pragma unroll
      for (int mi = 0; mi < 2; ++mi){
        int row = 32*w + 16*mi + c;
        int byt = (row*256 + kt*64 + g*16) ^ ((row & 7) << 4);
        pa[mi] = *(const short8*)((char*)lP + byt);
      }
      #pragma unroll
      for (int dn = 0; dn < 4; ++dn){
        int d = dn*16 + c;
        int byt = (d*256 + kt*64 + g*16) ^ ((((d >> 3) ^ d) & 7) << 4);
        vb[dn] = *(const short8*)((char*)lV + byt);
      }
      #pragma unroll
      for (int mi = 0; mi < 2; ++mi)
        #pragma unroll
        for (int dn = 0; dn < 4; ++dn)
          oacc[mi][dn] = MFMA16(pa[mi], vb[dn], oacc[mi][dn]);
    }
    __syncthreads();
  }

  // ---- epilogue: normalize, store o[B,S,H*D] bf16 ----
  #pragma unroll
  for (int mi = 0; mi < 2; ++mi){
    #pragma unroll
    for (int r = 0; r < 4; ++r){
      float inv = 1.0f / l_s[mi][r];
      int qp = 32*w + 16*mi + 4*g + r;
      size_t orow = ((size_t)(b*8192 + n*128 + qp)) * 512 + h*64;
      #pragma unroll
      for (int dn = 0; dn < 4; ++dn)
        Og[orow + dn*16 + c] = f2bf(oacc[mi][dn][r] * inv);
    }
  }
}

extern "C" void kernel_launch(void* const* d_in, const int* in_sizes, int n_in,
                              void* d_out, int out_size, void* d_ws, size_t ws_size,
                              hipStream_t stream) {
  const float* inq  = (const float*)d_in[0];
  const float* inkv = (const float*)d_in[1];
  const float* Wq   = (const float*)d_in[2];
  const float* bq   = (const float*)d_in[3];
  const float* Wk   = (const float*)d_in[4];
  const float* bk   = (const float*)d_in[5];
  const float* Wv   = (const float*)d_in[6];
  const float* bv   = (const float*)d_in[7];
  const float* Wo   = (const float*)d_in[8];
  const float* bo   = (const float*)d_in[9];

  // workspace layout (bytes); total 82 MB
  char* ws = (char*)d_ws;
  u16* Xq  = (u16*)(ws + 0);                       // 16 MB  [16384,512] bf16
  u16* Xkv = (u16*)(ws + ((size_t)16 << 20));      // 16 MB
  u16* qb  = (u16*)(ws + ((size_t)32 << 20));      // 16 MB  [B,H,S,D] bf16
  u16* kbf = (u16*)(ws + ((size_t)48 << 20));      // 16 MB
  u16* vbf = (u16*)(ws + ((size_t)64 << 20));      // 16 MB
  u16* wT  = (u16*)(ws + ((size_t)80 << 20));      // 2 MB   4x [512,512] bf16 (transposed)
  u16* ob  = (u16*)(ws + 0);                       // reuse Xq slot (dead after gemm q)

  cvt_x<<<8192, 256, 0, stream>>>(inq,  Xq);
  cvt_x<<<8192, 256, 0, stream>>>(inkv, Xkv);
  wtrans<<<dim3(16,16,4), dim3(32,8), 0, stream>>>(Wq, Wk, Wv, Wo, wT);

  gemm512<<<dim3(128,4), 256, 0, stream>>>(Xq,  wT,            bq, qb,  nullptr, 0);
  gemm512<<<dim3(128,4), 256, 0, stream>>>(Xkv, wT + 262144,   bk, kbf, nullptr, 0);
  gemm512<<<dim3(128,4), 256, 0, stream>>>(Xkv, wT + 2*262144, bv, vbf, nullptr, 0);

  attn64<<<dim3(64,8,2), 256, 0, stream>>>(qb, kbf, vbf, ob);

  gemm512<<<dim3(128,4), 256, 0, stream>>>(ob, wT + 3*262144, bo, nullptr, (float*)d_out, 1);
}

// Round 2
// 144.125 us; speedup vs baseline: 1.2949x; 1.2949x over previous
//
#include <hip/hip_runtime.h>

typedef unsigned short u16;
typedef unsigned int u32;
typedef __attribute__((ext_vector_type(8))) short short8;
typedef __attribute__((ext_vector_type(4))) float f32x4;
typedef __attribute__((ext_vector_type(4))) unsigned short u16x4;
typedef __attribute__((ext_vector_type(2))) unsigned int u32x2;

#define MFMA16(a,b,c) __builtin_amdgcn_mfma_f32_16x16x32_bf16((a),(b),(c),0,0,0)

__device__ __forceinline__ u16 f2bf(float x){
  union { float f; unsigned u; } un; un.f = x;
  unsigned r = un.u + 0x7fffu + ((un.u >> 16) & 1u);
  return (u16)(r >> 16);
}

// ---------------- f32 -> bf16 convert (activations) ----------------
__global__ __launch_bounds__(256) void cvt_x(const float* __restrict__ in, u16* __restrict__ out){
  int i = (blockIdx.x * 256 + threadIdx.x) * 4;
  f32x4 v = *(const f32x4*)(in + i);
  u16x4 r = { f2bf(v[0]), f2bf(v[1]), f2bf(v[2]), f2bf(v[3]) };
  *(u16x4*)(out + i) = r;
}

// ---------------- weight transpose+convert: out[n][k] = in[k][n], 512x512 ----------------
__global__ __launch_bounds__(256) void wtrans(const float* __restrict__ W0, const float* __restrict__ W1,
                                              const float* __restrict__ W2, const float* __restrict__ W3,
                                              u16* __restrict__ out){
  __shared__ float tile[32][33];
  const float* src = (blockIdx.z == 0) ? W0 : (blockIdx.z == 1) ? W1 : (blockIdx.z == 2) ? W2 : W3;
  u16* dst = out + (size_t)blockIdx.z * 262144;
  int k0 = blockIdx.x * 32, n0 = blockIdx.y * 32;
  int tx = threadIdx.x, ty = threadIdx.y;
  #pragma unroll
  for (int i = 0; i < 4; ++i)
    tile[ty + 8*i][tx] = src[(size_t)(k0 + ty + 8*i)*512 + n0 + tx];
  __syncthreads();
  #pragma unroll
  for (int i = 0; i < 4; ++i)
    dst[(size_t)(n0 + ty + 8*i)*512 + k0 + tx] = f2bf(tile[tx][ty + 8*i]);
}

// ---------------- GEMM: C[M,512] = A[M,512](bf16) * BT[512,512]^T(bf16) + bias ----------------
// mode 0: bf16 out remapped to [B,H,S,D]  (row=b*8192+s, col=h*64+d)
// mode 1: f32 out, plain row-major [M,512]
// mode 2: bf16 out transposed: vT[(b*512+col)*8192 + s]  (i.e. [B*H, D, S])
__global__ __launch_bounds__(256) void gemm512(const u16* __restrict__ A, const u16* __restrict__ BT,
                                               const float* __restrict__ bias,
                                               u16* __restrict__ outb, float* __restrict__ outf, int mode){
  __shared__ u16 lA[128*32];
  __shared__ u16 lB[128*32];
  const int tid = threadIdx.x, lane = tid & 63, w = tid >> 6;
  const int g = lane >> 4, c = lane & 15;
  const int bm = blockIdx.x, bn = blockIdx.y;
  const int wm = (w >> 1) * 64, wn = (w & 1) * 64;
  f32x4 acc[4][4];
  #pragma unroll
  for (int mi = 0; mi < 4; ++mi)
    #pragma unroll
    for (int ni = 0; ni < 4; ++ni){ f32x4 z = {0.f,0.f,0.f,0.f}; acc[mi][ni] = z; }

  for (int kt = 0; kt < 16; ++kt){
    #pragma unroll
    for (int j = 0; j < 2; ++j){
      int lrow = 32*w + 16*j;
      const u16* ga = A  + (size_t)(bm*128 + lrow + (lane >> 2))*512 + kt*32 + (lane & 3)*8;
      __builtin_amdgcn_global_load_lds((const __attribute__((address_space(1))) void*)ga,
          (__attribute__((address_space(3))) void*)&lA[lrow*32], 16, 0, 0);
      const u16* gb = BT + (size_t)(bn*128 + lrow + (lane >> 2))*512 + kt*32 + (lane & 3)*8;
      __builtin_amdgcn_global_load_lds((const __attribute__((address_space(1))) void*)gb,
          (__attribute__((address_space(3))) void*)&lB[lrow*32], 16, 0, 0);
    }
    __syncthreads();
    short8 af[4], bf[4];
    #pragma unroll
    for (int i = 0; i < 4; ++i){
      af[i] = *(const short8*)&lA[(wm + 16*i + c)*32 + g*8];
      bf[i] = *(const short8*)&lB[(wn + 16*i + c)*32 + g*8];
    }
    #pragma unroll
    for (int mi = 0; mi < 4; ++mi)
      #pragma unroll
      for (int ni = 0; ni < 4; ++ni)
        acc[mi][ni] = MFMA16(af[mi], bf[ni], acc[mi][ni]);
    __syncthreads();
  }

  #pragma unroll
  for (int mi = 0; mi < 4; ++mi){
    #pragma unroll
    for (int ni = 0; ni < 4; ++ni){
      int col = bn*128 + wn + 16*ni + c;
      float bv = bias[col];
      #pragma unroll
      for (int r = 0; r < 4; ++r){
        int row = bm*128 + wm + 16*mi + 4*g + r;
        float v = acc[mi][ni][r] + bv;
        if (mode == 0){
          int bb = row >> 13, s = row & 8191, hh = col >> 6, d = col & 63;
          outb[((size_t)(bb*8 + hh)*8192 + s)*64 + d] = f2bf(v);
        } else if (mode == 1){
          outf[(size_t)row*512 + col] = v;
        } else {
          int bb = row >> 13, s = row & 8191;
          outb[((size_t)(bb*512 + col) << 13) + s] = f2bf(v);
        }
      }
    }
  }
}

// ---------------- banded flash attention, 8 waves x 16 q-rows ----------------
// grid (nb=64, H=8, B=2), 512 threads.
// Q,K in [B,H,S,D] bf16; VT in [B*H, D=64, S] bf16; O out [B,S,H*D] bf16.
__global__ __launch_bounds__(512, 4) void attn8(const u16* __restrict__ Qg, const u16* __restrict__ Kg,
                                                const u16* __restrict__ VTg, u16* __restrict__ Og){
  __shared__ u16 lK[128*64];    // 16 KB  [key][d], slot-swizzled ^((key&7)<<4)
  __shared__ u16 lVT[64*128];   // 16 KB  [d][key], slot-swizzled ^((d&7)<<4)
  __shared__ u16 lP[128*128];   // 32 KB  [q][key], per-wave-private rows, ^((q&7)<<4)
  const int tid = threadIdx.x, lane = tid & 63, w = tid >> 6;
  const int g = lane >> 4, c = lane & 15;
  const int n = blockIdx.x, h = blockIdx.y, b = blockIdx.z;
  const size_t baseq = ((size_t)(b*8 + h)) << 19;        // * 8192 * 64
  const size_t basev = ((size_t)((b*8 + h)*64)) << 13;   // row d stride 8192

  // Q as B-operand: lane (c,g) holds Q[q0w + c][dt*32 + g*8 + j]
  short8 qf0, qf1;
  {
    const u16* qp = Qg + baseq + (size_t)(n*128 + w*16 + c)*64 + g*8;
    qf0 = *(const short8*)qp;
    qf1 = *(const short8*)(qp + 32);
  }

  float m_run = -1e30f, l_run = 0.f;
  f32x4 oacc[4];
  #pragma unroll
  for (int dn = 0; dn < 4; ++dn){ f32x4 z = {0.f,0.f,0.f,0.f}; oacc[dn] = z; }

  const int lo = (n == 0) ? 1 : 0;
  const int hi = (n == 63) ? 1 : 2;

  // staging thread mapping
  const int sr = tid >> 2, sq = tid & 3;   // K: row sr (0..127), 32B chunk sq
  const int vd = tid >> 3, vc = tid & 7;   // VT: row vd (0..63), 32B chunk vc

  short8 kr0, kr1, vr0, vr1;
  {
    int kstart = n*128 + (lo - 1)*128;
    const u16* kp = Kg + baseq + (size_t)(kstart + sr)*64 + sq*16;
    kr0 = *(const short8*)kp; kr1 = *(const short8*)(kp + 8);
    const u16* vp = VTg + basev + ((size_t)vd << 13) + kstart + vc*16;
    vr0 = *(const short8*)vp; vr1 = *(const short8*)(vp + 8);
  }

  const int prow = w*16 + c;
  const float SCL = 0.125f * 1.44269504f;

  for (int kb = lo; kb <= hi; ++kb){
    // ---- commit staged regs to LDS ----
    {
      int byt = sr*128 + ((sq*32) ^ ((sr & 7) << 4));
      *(short8*)((char*)lK + byt) = kr0;
      byt = sr*128 + ((sq*32 + 16) ^ ((sr & 7) << 4));
      *(short8*)((char*)lK + byt) = kr1;
      int byt2 = vd*256 + ((vc*32) ^ ((vd & 7) << 4));
      *(short8*)((char*)lVT + byt2) = vr0;
      byt2 = vd*256 + ((vc*32 + 16) ^ ((vd & 7) << 4));
      *(short8*)((char*)lVT + byt2) = vr1;
    }
    __syncthreads();

    // ---- async prefetch next kb tile into regs (lands under compute) ----
    if (kb < hi){
      int kstart = n*128 + kb*128;
      const u16* kp = Kg + baseq + (size_t)(kstart + sr)*64 + sq*16;
      kr0 = *(const short8*)kp; kr1 = *(const short8*)(kp + 8);
      const u16* vp = VTg + basev + ((size_t)vd << 13) + kstart + vc*16;
      vr0 = *(const short8*)vp; vr1 = *(const short8*)(vp + 8);
    }

    // ---- S^T = K * Q^T  (swapped operands: lane owns one q-row = c) ----
    f32x4 st[8];
    #pragma unroll
    for (int nt = 0; nt < 8; ++nt){ f32x4 z = {0.f,0.f,0.f,0.f}; st[nt] = z; }
    #pragma unroll
    for (int nt = 0; nt < 8; ++nt){
      int row = nt*16 + c;
      int swz = (row & 7) << 4;
      short8 kf0 = *(const short8*)((char*)lK + row*128 + ((g*16) ^ swz));
      short8 kf1 = *(const short8*)((char*)lK + row*128 + ((64 + g*16) ^ swz));
      st[nt] = MFMA16(kf0, qf0, st[nt]);
      st[nt] = MFMA16(kf1, qf1, st[nt]);
    }

    // ---- band mask + online softmax (log2 domain); key = koff0 + nt*16+4g+r ----
    int koff = (kb - 1)*128 - (w*16 + c);   // rel position of key vs this lane's q
    float mx = -1e30f;
    #pragma unroll
    for (int nt = 0; nt < 8; ++nt)
      #pragma unroll
      for (int r = 0; r < 4; ++r){
        int rel = koff + nt*16 + 4*g + r;
        float s = (rel >= -128 && rel <= 127) ? st[nt][r] * SCL : -1e30f;
        st[nt][r] = s;
        mx = fmaxf(mx, s);
      }
    mx = fmaxf(mx, __shfl_xor(mx, 16));
    mx = fmaxf(mx, __shfl_xor(mx, 32));
    float mnew = fmaxf(m_run, mx);
    float fac = __builtin_amdgcn_exp2f(m_run - mnew);
    m_run = mnew;
    float rs = 0.f;
    #pragma unroll
    for (int nt = 0; nt < 8; ++nt)
      #pragma unroll
      for (int r = 0; r < 4; ++r){
        float p = __builtin_amdgcn_exp2f(st[nt][r] - mnew);
        st[nt][r] = p; rs += p;
      }
    rs += __shfl_xor(rs, 16);
    rs += __shfl_xor(rs, 32);
    l_run = l_run * fac + rs;
    // rescale O rows q'=4g+r with fac from lane c'=4g+r (same g)
    #pragma unroll
    for (int r = 0; r < 4; ++r){
      float fr = __shfl(fac, g*20 + r);
      #pragma unroll
      for (int dn = 0; dn < 4; ++dn) oacc[dn][r] *= fr;
    }

    // ---- P -> LDS (bf16, b64 per key-tile; wave-private rows, no barrier) ----
    #pragma unroll
    for (int nt = 0; nt < 8; ++nt){
      u32 plo, phi;
      asm volatile("v_cvt_pk_bf16_f32 %0, %1, %2" : "=v"(plo) : "v"(st[nt][0]), "v"(st[nt][1]));
      asm volatile("v_cvt_pk_bf16_f32 %0, %1, %2" : "=v"(phi) : "v"(st[nt][2]), "v"(st[nt][3]));
      u32x2 pv = { plo, phi };
      int byt = prow*256 + ((nt*32 + g*8) ^ ((c & 7) << 4));
      *(u32x2*)((char*)lP + byt) = pv;
    }

    // ---- O += P V ----
    #pragma unroll
    for (int kt = 0; kt < 4; ++kt){
      short8 pa = *(const short8*)((char*)lP + prow*256 + ((kt*64 + g*16) ^ ((c & 7) << 4)));
      #pragma unroll
      for (int dn = 0; dn < 4; ++dn){
        int dd = dn*16 + c;
        short8 vb = *(const short8*)((char*)lVT + dd*256 + ((kt*64 + g*16) ^ ((c & 7) << 4)));
        oacc[dn] = MFMA16(pa, vb, oacc[dn]);
      }
    }
    __syncthreads();
  }

  // ---- epilogue: normalize, store o[B,S,H*D] bf16 ----
  #pragma unroll
  for (int r = 0; r < 4; ++r){
    float li = __shfl(l_run, g*20 + r);
    float inv = 1.0f / li;
    size_t orow = ((size_t)(b*8192 + n*128 + w*16 + 4*g + r))*512 + h*64 + c;
    #pragma unroll
    for (int dn = 0; dn < 4; ++dn)
      Og[orow + dn*16] = f2bf(oacc[dn][r] * inv);
  }
}

extern "C" void kernel_launch(void* const* d_in, const int* in_sizes, int n_in,
                              void* d_out, int out_size, void* d_ws, size_t ws_size,
                              hipStream_t stream) {
  const float* inq  = (const float*)d_in[0];
  const float* inkv = (const float*)d_in[1];
  const float* Wq   = (const float*)d_in[2];
  const float* bq   = (const float*)d_in[3];
  const float* Wk   = (const float*)d_in[4];
  const float* bk   = (const float*)d_in[5];
  const float* Wv   = (const float*)d_in[6];
  const float* bv   = (const float*)d_in[7];
  const float* Wo   = (const float*)d_in[8];
  const float* bo   = (const float*)d_in[9];

  // workspace layout (bytes); total 82 MB
  char* ws = (char*)d_ws;
  u16* Xq  = (u16*)(ws + 0);                       // 16 MB  [16384,512] bf16
  u16* Xkv = (u16*)(ws + ((size_t)16 << 20));      // 16 MB
  u16* qb  = (u16*)(ws + ((size_t)32 << 20));      // 16 MB  [B,H,S,D] bf16
  u16* kbf = (u16*)(ws + ((size_t)48 << 20));      // 16 MB  [B,H,S,D] bf16
  u16* vT  = (u16*)(ws + ((size_t)64 << 20));      // 16 MB  [B*H,D,S] bf16
  u16* wT  = (u16*)(ws + ((size_t)80 << 20));      // 2 MB   4x [512,512] bf16 (transposed)
  u16* ob  = (u16*)(ws + 0);                       // reuse Xq slot (dead after Q gemm)

  cvt_x<<<8192, 256, 0, stream>>>(inq,  Xq);
  cvt_x<<<8192, 256, 0, stream>>>(inkv, Xkv);
  wtrans<<<dim3(16,16,4), dim3(32,8), 0, stream>>>(Wq, Wk, Wv, Wo, wT);

  gemm512<<<dim3(128,4), 256, 0, stream>>>(Xq,  wT,            bq, qb,  nullptr, 0);
  gemm512<<<dim3(128,4), 256, 0, stream>>>(Xkv, wT + 262144,   bk, kbf, nullptr, 0);
  gemm512<<<dim3(128,4), 256, 0, stream>>>(Xkv, wT + 2*262144, bv, vT,  nullptr, 2);

  attn8<<<dim3(64,8,2), 512, 0, stream>>>(qb, kbf, vT, ob);

  gemm512<<<dim3(128,4), 256, 0, stream>>>(ob, wT + 3*262144, bo, nullptr, (float*)d_out, 1);
}

// Round 3
// 108.247 us; speedup vs baseline: 1.7241x; 1.3315x over previous
//
#include <hip/hip_runtime.h>

typedef unsigned short u16;
typedef unsigned int u32;
typedef __attribute__((ext_vector_type(8))) short short8;
typedef __attribute__((ext_vector_type(4))) float f32x4;
typedef __attribute__((ext_vector_type(4))) unsigned short u16x4;
typedef __attribute__((ext_vector_type(2))) unsigned int u32x2;

#define MFMA16(a,b,c) __builtin_amdgcn_mfma_f32_16x16x32_bf16((a),(b),(c),0,0,0)
#define AS3(p) ((__attribute__((address_space(3))) void*)(p))
#define AS1(p) ((const __attribute__((address_space(1))) void*)(p))

__device__ __forceinline__ u16 f2bf(float x){
  union { float f; unsigned u; } un; un.f = x;
  unsigned r = un.u + 0x7fffu + ((un.u >> 16) & 1u);
  return (u16)(r >> 16);
}

// ---------------- f32 -> bf16 convert (both activation tensors, one dispatch) ----------------
__global__ __launch_bounds__(256) void cvt2(const float* __restrict__ q, const float* __restrict__ kv,
                                            u16* __restrict__ oq, u16* __restrict__ okv){
  int bi = blockIdx.x;
  const float* in = (bi < 8192) ? q : kv;
  u16* out = (bi < 8192) ? oq : okv;
  int i = ((bi & 8191) * 256 + threadIdx.x) * 4;
  f32x4 v = *(const f32x4*)(in + i);
  u16x4 r = { f2bf(v[0]), f2bf(v[1]), f2bf(v[2]), f2bf(v[3]) };
  *(u16x4*)(out + i) = r;
}

// ---------------- weight transpose+convert: out[n][k] = in[k][n], 512x512 ----------------
__global__ __launch_bounds__(256) void wtrans(const float* __restrict__ W0, const float* __restrict__ W1,
                                              const float* __restrict__ W2, const float* __restrict__ W3,
                                              u16* __restrict__ out){
  __shared__ float tile[32][33];
  const float* src = (blockIdx.z == 0) ? W0 : (blockIdx.z == 1) ? W1 : (blockIdx.z == 2) ? W2 : W3;
  u16* dst = out + (size_t)blockIdx.z * 262144;
  int k0 = blockIdx.x * 32, n0 = blockIdx.y * 32;
  int tx = threadIdx.x, ty = threadIdx.y;
  #pragma unroll
  for (int i = 0; i < 4; ++i)
    tile[ty + 8*i][tx] = src[(size_t)(k0 + ty + 8*i)*512 + n0 + tx];
  __syncthreads();
  #pragma unroll
  for (int i = 0; i < 4; ++i)
    dst[(size_t)(n0 + ty + 8*i)*512 + k0 + tx] = f2bf(tile[tx][ty + 8*i]);
}

// ---------------- shared GEMM core: C[128,128] tile of A[M,512]*BT[512,512]^T + bias ----------------
// mode 0: bf16 out remapped to [B,H,S,D]  (row=b*8192+s, col=h*64+d), via LDS repack
// mode 1: f32 out, plain row-major [M,512], direct stores
// mode 2: bf16 out transposed vT[(b*512+col)*8192 + s], via LDS repack
__device__ __forceinline__ void gemm_core(u16* sm, const u16* __restrict__ A, const u16* __restrict__ BT,
                                          const float* __restrict__ bias,
                                          u16* __restrict__ outb, float* __restrict__ outf,
                                          int mode, int bm, int bn){
  const int tid = threadIdx.x, lane = tid & 63, w = tid >> 6;
  const int g = lane >> 4, c = lane & 15;
  const int wm = (w >> 1) * 64, wn = (w & 1) * 64;
  const int srow = lane >> 2, scol = (lane & 3) * 8;
  f32x4 acc[4][4];
  #pragma unroll
  for (int mi = 0; mi < 4; ++mi)
    #pragma unroll
    for (int ni = 0; ni < 4; ++ni){ f32x4 z = {0.f,0.f,0.f,0.f}; acc[mi][ni] = z; }

  auto stage = [&](int buf, int kt){
    #pragma unroll
    for (int j = 0; j < 2; ++j){
      int lrow = 32*w + 16*j;
      const u16* ga = A + (size_t)(bm*128 + lrow + srow)*512 + kt*32 + scol;
      __builtin_amdgcn_global_load_lds(AS1(ga), AS3(sm + (buf*2 + 0)*4096 + lrow*32), 16, 0, 0);
      const u16* gb = BT + (size_t)(bn*128 + lrow + srow)*512 + kt*32 + scol;
      __builtin_amdgcn_global_load_lds(AS1(gb), AS3(sm + (buf*2 + 1)*4096 + lrow*32), 16, 0, 0);
    }
  };

  stage(0, 0);
  int cur = 0;
  for (int kt = 0; kt < 16; ++kt){
    __syncthreads();                       // drains stage into sm[cur] (issued last iter)
    if (kt < 15) stage(cur ^ 1, kt + 1);   // prefetch next tile, lands under this compute
    const u16* baseA = sm + (cur*2 + 0)*4096;
    const u16* baseB = sm + (cur*2 + 1)*4096;
    short8 af[4], bf[4];
    #pragma unroll
    for (int i = 0; i < 4; ++i){
      af[i] = *(const short8*)&baseA[(wm + 16*i + c)*32 + g*8];
      bf[i] = *(const short8*)&baseB[(wn + 16*i + c)*32 + g*8];
    }
    #pragma unroll
    for (int mi = 0; mi < 4; ++mi)
      #pragma unroll
      for (int ni = 0; ni < 4; ++ni)
        acc[mi][ni] = MFMA16(af[mi], bf[ni], acc[mi][ni]);
    cur ^= 1;
  }
  __syncthreads();   // staging buffers dead; sm reused as 128x128 bf16 epilogue tile

  const int lane3 = tid & 7;
  if (mode == 0){
    // tile[row][col] row-major 256B rows, XOR-swizzled
    #pragma unroll
    for (int mi = 0; mi < 4; ++mi)
      #pragma unroll
      for (int ni = 0; ni < 4; ++ni){
        int colL = wn + 16*ni + c;
        float bv = bias[bn*128 + colL];
        #pragma unroll
        for (int r = 0; r < 4; ++r){
          int rowL = wm + 16*mi + 4*g + r;
          int byt = rowL*256 + ((colL*2) ^ ((rowL & 7) << 4));
          *(u16*)((char*)sm + byt) = f2bf(acc[mi][ni][r] + bv);
        }
      }
    __syncthreads();
    #pragma unroll
    for (int p = 0; p < 8; ++p){
      int rh = (tid >> 3) + p*32;
      int rowL = rh >> 1, half = rh & 1;
      int byt = rowL*256 + ((half*128 + lane3*16) ^ ((rowL & 7) << 4));
      short8 vdat = *(const short8*)((char*)sm + byt);
      int rowG = bm*128 + rowL;
      int bb = rowG >> 13, s = rowG & 8191;
      int hh = bn*2 + half;
      *(short8*)(outb + (((size_t)(bb*8 + hh)*8192 + s) << 6) + lane3*8) = vdat;
    }
  } else if (mode == 2){
    // tile[col][row] col-major 256B rows, XOR-swizzled; frag rows are contiguous -> 8B packed writes
    #pragma unroll
    for (int mi = 0; mi < 4; ++mi)
      #pragma unroll
      for (int ni = 0; ni < 4; ++ni){
        int colL = wn + 16*ni + c;
        float bv = bias[bn*128 + colL];
        u16x4 pk = { f2bf(acc[mi][ni][0] + bv), f2bf(acc[mi][ni][1] + bv),
                     f2bf(acc[mi][ni][2] + bv), f2bf(acc[mi][ni][3] + bv) };
        int row0 = wm + 16*mi + 4*g;
        int byt = colL*256 + ((row0*2) ^ ((colL & 7) << 4));
        *(u16x4*)((char*)sm + byt) = pk;
      }
    __syncthreads();
    #pragma unroll
    for (int p = 0; p < 8; ++p){
      int rh = (tid >> 3) + p*32;
      int colL = rh >> 1, half = rh & 1;
      int byt = colL*256 + ((half*128 + lane3*16) ^ ((colL & 7) << 4));
      short8 vdat = *(const short8*)((char*)sm + byt);
      int rowG0 = bm*128 + half*64 + lane3*8;
      int bb = rowG0 >> 13, s = rowG0 & 8191;
      int colG = bn*128 + colL;
      *(short8*)(outb + (((size_t)(bb*512 + colG)) << 13) + s) = vdat;
    }
  } else {
    #pragma unroll
    for (int mi = 0; mi < 4; ++mi)
      #pragma unroll
      for (int ni = 0; ni < 4; ++ni){
        int col = bn*128 + wn + 16*ni + c;
        float bv = bias[col];
        #pragma unroll
        for (int r = 0; r < 4; ++r){
          int row = bm*128 + wm + 16*mi + 4*g + r;
          outf[(size_t)row*512 + col] = acc[mi][ni][r] + bv;
        }
      }
  }
}

// merged QKV projection: grid (128, 12); bn 0-3 -> Q, 4-7 -> K, 8-11 -> V^T
__global__ __launch_bounds__(256, 4) void gemm_qkv(const u16* __restrict__ Xq, const u16* __restrict__ Xkv,
                                                   const u16* __restrict__ wT,
                                                   const float* __restrict__ bq, const float* __restrict__ bk,
                                                   const float* __restrict__ bv,
                                                   u16* __restrict__ qb, u16* __restrict__ kbf, u16* __restrict__ vT){
  __shared__ u16 sm[4*4096];
  int bn = blockIdx.y, which = bn >> 2, bnn = bn & 3;
  const u16* A = which ? Xkv : Xq;
  const u16* BT = wT + which*262144;
  const float* bias = (which == 0) ? bq : (which == 1) ? bk : bv;
  u16* outb = (which == 0) ? qb : (which == 1) ? kbf : vT;
  int mode = (which == 2) ? 2 : 0;
  gemm_core(sm, A, BT, bias, outb, nullptr, mode, blockIdx.x, bnn);
}

// output projection: grid (128, 4), f32 out
__global__ __launch_bounds__(256, 4) void gemm_out(const u16* __restrict__ A, const u16* __restrict__ BT,
                                                   const float* __restrict__ bias, float* __restrict__ outf){
  __shared__ u16 sm[4*4096];
  gemm_core(sm, A, BT, bias, nullptr, outf, 1, blockIdx.x, blockIdx.y);
}

// ---------------- banded flash attention, 8 waves x 16 q-rows ----------------
__global__ __launch_bounds__(512, 4) void attn8(const u16* __restrict__ Qg, const u16* __restrict__ Kg,
                                                const u16* __restrict__ VTg, u16* __restrict__ Og){
  __shared__ u16 lK[128*64];
  __shared__ u16 lVT[64*128];
  __shared__ u16 lP[128*128];
  const int tid = threadIdx.x, lane = tid & 63, w = tid >> 6;
  const int g = lane >> 4, c = lane & 15;
  const int n = blockIdx.x, h = blockIdx.y, b = blockIdx.z;
  const size_t baseq = ((size_t)(b*8 + h)) << 19;
  const size_t basev = ((size_t)((b*8 + h)*64)) << 13;

  short8 qf0, qf1;
  {
    const u16* qp = Qg + baseq + (size_t)(n*128 + w*16 + c)*64 + g*8;
    qf0 = *(const short8*)qp;
    qf1 = *(const short8*)(qp + 32);
  }

  float m_run = -1e30f, l_run = 0.f;
  f32x4 oacc[4];
  #pragma unroll
  for (int dn = 0; dn < 4; ++dn){ f32x4 z = {0.f,0.f,0.f,0.f}; oacc[dn] = z; }

  const int lo = (n == 0) ? 1 : 0;
  const int hi = (n == 63) ? 1 : 2;

  const int sr = tid >> 2, sq = tid & 3;
  const int vd = tid >> 3, vc = tid & 7;

  short8 kr0, kr1, vr0, vr1;
  {
    int kstart = n*128 + (lo - 1)*128;
    const u16* kp = Kg + baseq + (size_t)(kstart + sr)*64 + sq*16;
    kr0 = *(const short8*)kp; kr1 = *(const short8*)(kp + 8);
    const u16* vp = VTg + basev + ((size_t)vd << 13) + kstart + vc*16;
    vr0 = *(const short8*)vp; vr1 = *(const short8*)(vp + 8);
  }

  const int prow = w*16 + c;
  const float SCL = 0.125f * 1.44269504f;

  for (int kb = lo; kb <= hi; ++kb){
    {
      int byt = sr*128 + ((sq*32) ^ ((sr & 7) << 4));
      *(short8*)((char*)lK + byt) = kr0;
      byt = sr*128 + ((sq*32 + 16) ^ ((sr & 7) << 4));
      *(short8*)((char*)lK + byt) = kr1;
      int byt2 = vd*256 + ((vc*32) ^ ((vd & 7) << 4));
      *(short8*)((char*)lVT + byt2) = vr0;
      byt2 = vd*256 + ((vc*32 + 16) ^ ((vd & 7) << 4));
      *(short8*)((char*)lVT + byt2) = vr1;
    }
    __syncthreads();

    if (kb < hi){
      int kstart = n*128 + kb*128;
      const u16* kp = Kg + baseq + (size_t)(kstart + sr)*64 + sq*16;
      kr0 = *(const short8*)kp; kr1 = *(const short8*)(kp + 8);
      const u16* vp = VTg + basev + ((size_t)vd << 13) + kstart + vc*16;
      vr0 = *(const short8*)vp; vr1 = *(const short8*)(vp + 8);
    }

    f32x4 st[8];
    #pragma unroll
    for (int nt = 0; nt < 8; ++nt){ f32x4 z = {0.f,0.f,0.f,0.f}; st[nt] = z; }
    #pragma unroll
    for (int nt = 0; nt < 8; ++nt){
      int row = nt*16 + c;
      int swz = (row & 7) << 4;
      short8 kf0 = *(const short8*)((char*)lK + row*128 + ((g*16) ^ swz));
      short8 kf1 = *(const short8*)((char*)lK + row*128 + ((64 + g*16) ^ swz));
      st[nt] = MFMA16(kf0, qf0, st[nt]);
      st[nt] = MFMA16(kf1, qf1, st[nt]);
    }

    int koff = (kb - 1)*128 - (w*16 + c);
    float mx = -1e30f;
    #pragma unroll
    for (int nt = 0; nt < 8; ++nt)
      #pragma unroll
      for (int r = 0; r < 4; ++r){
        int rel = koff + nt*16 + 4*g + r;
        float s = (rel >= -128 && rel <= 127) ? st[nt][r] * SCL : -1e30f;
        st[nt][r] = s;
        mx = fmaxf(mx, s);
      }
    mx = fmaxf(mx, __shfl_xor(mx, 16));
    mx = fmaxf(mx, __shfl_xor(mx, 32));
    float mnew = fmaxf(m_run, mx);
    float fac = __builtin_amdgcn_exp2f(m_run - mnew);
    m_run = mnew;
    float rs = 0.f;
    #pragma unroll
    for (int nt = 0; nt < 8; ++nt)
      #pragma unroll
      for (int r = 0; r < 4; ++r){
        float p = __builtin_amdgcn_exp2f(st[nt][r] - mnew);
        st[nt][r] = p; rs += p;
      }
    rs += __shfl_xor(rs, 16);
    rs += __shfl_xor(rs, 32);
    l_run = l_run * fac + rs;
    #pragma unroll
    for (int r = 0; r < 4; ++r){
      float fr = __shfl(fac, g*20 + r);
      #pragma unroll
      for (int dn = 0; dn < 4; ++dn) oacc[dn][r] *= fr;
    }

    #pragma unroll
    for (int nt = 0; nt < 8; ++nt){
      u32 plo, phi;
      asm volatile("v_cvt_pk_bf16_f32 %0, %1, %2" : "=v"(plo) : "v"(st[nt][0]), "v"(st[nt][1]));
      asm volatile("v_cvt_pk_bf16_f32 %0, %1, %2" : "=v"(phi) : "v"(st[nt][2]), "v"(st[nt][3]));
      u32x2 pv = { plo, phi };
      int byt = prow*256 + ((nt*32 + g*8) ^ ((c & 7) << 4));
      *(u32x2*)((char*)lP + byt) = pv;
    }

    #pragma unroll
    for (int kt = 0; kt < 4; ++kt){
      short8 pa = *(const short8*)((char*)lP + prow*256 + ((kt*64 + g*16) ^ ((c & 7) << 4)));
      #pragma unroll
      for (int dn = 0; dn < 4; ++dn){
        int dd = dn*16 + c;
        short8 vb = *(const short8*)((char*)lVT + dd*256 + ((kt*64 + g*16) ^ ((c & 7) << 4)));
        oacc[dn] = MFMA16(pa, vb, oacc[dn]);
      }
    }
    __syncthreads();
  }

  #pragma unroll
  for (int r = 0; r < 4; ++r){
    float li = __shfl(l_run, g*20 + r);
    float inv = 1.0f / li;
    size_t orow = ((size_t)(b*8192 + n*128 + w*16 + 4*g + r))*512 + h*64 + c;
    #pragma unroll
    for (int dn = 0; dn < 4; ++dn)
      Og[orow + dn*16] = f2bf(oacc[dn][r] * inv);
  }
}

extern "C" void kernel_launch(void* const* d_in, const int* in_sizes, int n_in,
                              void* d_out, int out_size, void* d_ws, size_t ws_size,
                              hipStream_t stream) {
  const float* inq  = (const float*)d_in[0];
  const float* inkv = (const float*)d_in[1];
  const float* Wq   = (const float*)d_in[2];
  const float* bq   = (const float*)d_in[3];
  const float* Wk   = (const float*)d_in[4];
  const float* bk   = (const float*)d_in[5];
  const float* Wv   = (const float*)d_in[6];
  const float* bv   = (const float*)d_in[7];
  const float* Wo   = (const float*)d_in[8];
  const float* bo   = (const float*)d_in[9];

  char* ws = (char*)d_ws;
  u16* Xq  = (u16*)(ws + 0);                       // 16 MB
  u16* Xkv = (u16*)(ws + ((size_t)16 << 20));      // 16 MB
  u16* qb  = (u16*)(ws + ((size_t)32 << 20));      // 16 MB [B,H,S,D]
  u16* kbf = (u16*)(ws + ((size_t)48 << 20));      // 16 MB [B,H,S,D]
  u16* vT  = (u16*)(ws + ((size_t)64 << 20));      // 16 MB [B*H,D,S]
  u16* wT  = (u16*)(ws + ((size_t)80 << 20));      // 2 MB
  u16* ob  = (u16*)(ws + 0);                       // reuse Xq slot

  cvt2<<<16384, 256, 0, stream>>>(inq, inkv, Xq, Xkv);
  wtrans<<<dim3(16,16,4), dim3(32,8), 0, stream>>>(Wq, Wk, Wv, Wo, wT);

  gemm_qkv<<<dim3(128,12), 256, 0, stream>>>(Xq, Xkv, wT, bq, bk, bv, qb, kbf, vT);

  attn8<<<dim3(64,8,2), 512, 0, stream>>>(qb, kbf, vT, ob);

  gemm_out<<<dim3(128,4), 256, 0, stream>>>(ob, wT + 3*262144, bo, (float*)d_out);
}

// Round 4
// 101.398 us; speedup vs baseline: 1.8405x; 1.0675x over previous
//
#include <hip/hip_runtime.h>

typedef unsigned short u16;
typedef unsigned int u32;
typedef __attribute__((ext_vector_type(8))) short short8;
typedef __attribute__((ext_vector_type(4))) float f32x4;
typedef __attribute__((ext_vector_type(4))) unsigned short u16x4;
typedef __attribute__((ext_vector_type(2))) unsigned int u32x2;

#define MFMA16(a,b,c) __builtin_amdgcn_mfma_f32_16x16x32_bf16((a),(b),(c),0,0,0)
#define AS3(p) ((__attribute__((address_space(3))) void*)(p))
#define AS1(p) ((const __attribute__((address_space(1))) void*)(p))

__device__ __forceinline__ u16 f2bf(float x){
  union { float f; unsigned u; } un; un.f = x;
  unsigned r = un.u + 0x7fffu + ((un.u >> 16) & 1u);
  return (u16)(r >> 16);
}

// ---------------- weight transpose+convert: out[n][k] = in[k][n], 512x512 ----------------
__global__ __launch_bounds__(256) void wtrans(const float* __restrict__ W0, const float* __restrict__ W1,
                                              const float* __restrict__ W2, const float* __restrict__ W3,
                                              u16* __restrict__ out){
  __shared__ float tile[32][33];
  const float* src = (blockIdx.z == 0) ? W0 : (blockIdx.z == 1) ? W1 : (blockIdx.z == 2) ? W2 : W3;
  u16* dst = out + (size_t)blockIdx.z * 262144;
  int k0 = blockIdx.x * 32, n0 = blockIdx.y * 32;
  int tx = threadIdx.x, ty = threadIdx.y;
  #pragma unroll
  for (int i = 0; i < 4; ++i)
    tile[ty + 8*i][tx] = src[(size_t)(k0 + ty + 8*i)*512 + n0 + tx];
  __syncthreads();
  #pragma unroll
  for (int i = 0; i < 4; ++i)
    dst[(size_t)(n0 + ty + 8*i)*512 + k0 + tx] = f2bf(tile[tx][ty + 8*i]);
}

// ---------------- shared GEMM core ----------------
// LDS map (u16 units): A bufs at buf*4096, B bufs at 8192 + buf*4096; all rows 32 u16 = 64 B,
// 16B chunks XOR-swizzled by ((row>>1)&3)<<4.
// MODE 0: f32 A, bf16 out -> [B,H,S,D];  MODE 2: f32 A, bf16 out -> vT[(b*512+col)*8192+s]
// MODE 1: bf16 A, f32 out row-major [M,512]
template<int MODE>
__device__ __forceinline__ void gemm_core(u16* sm, const void* Av, const u16* __restrict__ BT,
                                          const float* __restrict__ bias,
                                          u16* __restrict__ outb, float* __restrict__ outf,
                                          int bm, int bn){
  const int tid = threadIdx.x, lane = tid & 63, w = tid >> 6;
  const int g = lane >> 4, c = lane & 15;
  const int wm = (w >> 1) * 64, wn = (w & 1) * 64;
  f32x4 acc[4][4];
  #pragma unroll
  for (int mi = 0; mi < 4; ++mi)
    #pragma unroll
    for (int ni = 0; ni < 4; ++ni){ f32x4 z = {0.f,0.f,0.f,0.f}; acc[mi][ni] = z; }

  f32x4 ar[4];
  const float* Af = (const float*)Av;
  const u16*  Ab = (const u16*)Av;

  auto issueA = [&](int kt){   // f32 A -> regs (MODE 0/2)
    #pragma unroll
    for (int p = 0; p < 4; ++p){
      int row = p*32 + (tid >> 3);
      ar[p] = *(const f32x4*)(Af + (size_t)(bm*128 + row)*512 + kt*32 + (tid & 7)*4);
    }
  };
  auto writeA = [&](int buf){  // cvt + swizzled ds_write (MODE 0/2)
    #pragma unroll
    for (int p = 0; p < 4; ++p){
      int row = p*32 + (tid >> 3);
      u32 lo, hi;
      asm volatile("v_cvt_pk_bf16_f32 %0, %1, %2" : "=v"(lo) : "v"(ar[p][0]), "v"(ar[p][1]));
      asm volatile("v_cvt_pk_bf16_f32 %0, %1, %2" : "=v"(hi) : "v"(ar[p][2]), "v"(ar[p][3]));
      u32x2 pk = { lo, hi };
      int byt = buf*8192 + row*64 + (((tid & 7)*8) ^ (((row >> 1) & 3) << 4));
      *(u32x2*)((char*)sm + byt) = pk;
    }
  };
  auto stageAb = [&](int buf, int kt){  // bf16 A via pre-swizzled gload_lds (MODE 1)
    #pragma unroll
    for (int j = 0; j < 2; ++j){
      int lrow = 32*w + 16*j;
      int row = lrow + (lane >> 2);
      int f = (row >> 1) & 3;
      const u16* ga = Ab + (size_t)(bm*128 + row)*512 + kt*32 + ((lane & 3) ^ f)*8;
      __builtin_amdgcn_global_load_lds(AS1(ga), AS3(sm + buf*4096 + lrow*32), 16, 0, 0);
    }
  };
  auto stageB = [&](int buf, int kt){
    #pragma unroll
    for (int j = 0; j < 2; ++j){
      int lrow = 32*w + 16*j;
      int row = lrow + (lane >> 2);
      int f = (row >> 1) & 3;
      const u16* gb = BT + (size_t)(bn*128 + row)*512 + kt*32 + ((lane & 3) ^ f)*8;
      __builtin_amdgcn_global_load_lds(AS1(gb), AS3(sm + 8192 + buf*4096 + lrow*32), 16, 0, 0);
    }
  };

  // prologue
  if (MODE != 1){ issueA(0); stageB(0, 0); writeA(0); }
  else          { stageAb(0, 0); stageB(0, 0); }

  int buf = 0;
  for (int kt = 0; kt < 16; ++kt){
    __syncthreads();
    if (kt < 15){
      if (MODE != 1) issueA(kt + 1);
      stageB(buf ^ 1, kt + 1);
      if (MODE == 1) stageAb(buf ^ 1, kt + 1);
    }
    short8 af[4], bf[4];
    #pragma unroll
    for (int i = 0; i < 4; ++i){
      int rowA = wm + 16*i + c;
      af[i] = *(const short8*)((char*)sm + buf*8192 + rowA*64 + ((g*16) ^ (((rowA >> 1) & 3) << 4)));
      int rowB = wn + 16*i + c;
      bf[i] = *(const short8*)((char*)sm + 16384 + buf*8192 + rowB*64 + ((g*16) ^ (((rowB >> 1) & 3) << 4)));
    }
    #pragma unroll
    for (int mi = 0; mi < 4; ++mi)
      #pragma unroll
      for (int ni = 0; ni < 4; ++ni)
        acc[mi][ni] = MFMA16(af[mi], bf[ni], acc[mi][ni]);
    if (kt < 15 && MODE != 1) writeA(buf ^ 1);
    buf ^= 1;
  }
  __syncthreads();   // staging dead; sm reused for epilogue repack

  const int lane3 = tid & 7;
  if (MODE == 0){
    #pragma unroll
    for (int mi = 0; mi < 4; ++mi)
      #pragma unroll
      for (int ni = 0; ni < 4; ++ni){
        int colL = wn + 16*ni + c;
        float bv = bias[bn*128 + colL];
        #pragma unroll
        for (int r = 0; r < 4; ++r){
          int rowL = wm + 16*mi + 4*g + r;
          int byt = rowL*256 + ((colL*2) ^ ((rowL & 7) << 4));
          *(u16*)((char*)sm + byt) = f2bf(acc[mi][ni][r] + bv);
        }
      }
    __syncthreads();
    #pragma unroll
    for (int p = 0; p < 8; ++p){
      int rh = (tid >> 3) + p*32;
      int rowL = rh >> 1, half = rh & 1;
      int byt = rowL*256 + ((half*128 + lane3*16) ^ ((rowL & 7) << 4));
      short8 vdat = *(const short8*)((char*)sm + byt);
      int rowG = bm*128 + rowL;
      int bb = rowG >> 13, s = rowG & 8191;
      int hh = bn*2 + half;
      *(short8*)(outb + (((size_t)(bb*8 + hh)*8192 + s) << 6) + lane3*8) = vdat;
    }
  } else if (MODE == 2){
    #pragma unroll
    for (int mi = 0; mi < 4; ++mi)
      #pragma unroll
      for (int ni = 0; ni < 4; ++ni){
        int colL = wn + 16*ni + c;
        float bv = bias[bn*128 + colL];
        u16x4 pk = { f2bf(acc[mi][ni][0] + bv), f2bf(acc[mi][ni][1] + bv),
                     f2bf(acc[mi][ni][2] + bv), f2bf(acc[mi][ni][3] + bv) };
        int row0 = wm + 16*mi + 4*g;
        int byt = colL*256 + ((row0*2) ^ ((colL & 7) << 4));
        *(u16x4*)((char*)sm + byt) = pk;
      }
    __syncthreads();
    #pragma unroll
    for (int p = 0; p < 8; ++p){
      int rh = (tid >> 3) + p*32;
      int colL = rh >> 1, half = rh & 1;
      int byt = colL*256 + ((half*128 + lane3*16) ^ ((colL & 7) << 4));
      short8 vdat = *(const short8*)((char*)sm + byt);
      int rowG0 = bm*128 + half*64 + lane3*8;
      int bb = rowG0 >> 13, s = rowG0 & 8191;
      int colG = bn*128 + colL;
      *(short8*)(outb + (((size_t)(bb*512 + colG)) << 13) + s) = vdat;
    }
  } else {
    // f32 out via two 64-row LDS repack phases
    float* smf = (float*)sm;
    #pragma unroll
    for (int hh = 0; hh < 2; ++hh){
      if ((w >> 1) == hh){
        #pragma unroll
        for (int mi = 0; mi < 4; ++mi)
          #pragma unroll
          for (int ni = 0; ni < 4; ++ni){
            int colL = wn + 16*ni + c;
            float bv = bias[bn*128 + colL];
            #pragma unroll
            for (int r = 0; r < 4; ++r){
              int rowh = 16*mi + 4*g + r;
              int byt = rowh*512 + ((colL*4) ^ (((rowh >> 2) & 7) << 4));
              *(float*)((char*)smf + byt) = acc[mi][ni][r] + bv;
            }
          }
      }
      __syncthreads();
      #pragma unroll
      for (int p = 0; p < 8; ++p){
        int idx = p*256 + tid;
        int row = idx >> 5, chunk = idx & 31;
        int byt = row*512 + ((chunk*16) ^ (((row >> 2) & 7) << 4));
        f32x4 vdat = *(const f32x4*)((char*)smf + byt);
        *(f32x4*)(outf + (size_t)(bm*128 + hh*64 + row)*512 + bn*128 + chunk*4) = vdat;
      }
      __syncthreads();
    }
  }
}

// merged QKV projection, fused f32->bf16; 1D grid 1536, XCD-chunked, bn fastest in-chunk
__global__ __launch_bounds__(256, 4) void gemm_qkv(const float* __restrict__ Xq, const float* __restrict__ Xkv,
                                                   const u16* __restrict__ wT,
                                                   const float* __restrict__ bq, const float* __restrict__ bk,
                                                   const float* __restrict__ bv,
                                                   u16* __restrict__ qb, u16* __restrict__ kbf, u16* __restrict__ vT){
  __shared__ u16 sm[16384];
  int bi = blockIdx.x;
  int orig = (bi & 7)*192 + (bi >> 3);
  int bm = orig / 12, bn = orig % 12;
  int which = bn >> 2, bnn = bn & 3;
  const float* A = which ? Xkv : Xq;
  const u16* BT = wT + which*262144;
  const float* bias = (which == 0) ? bq : (which == 1) ? bk : bv;
  if (which == 2) gemm_core<2>(sm, A, BT, bias, vT, nullptr, bm, bnn);
  else            gemm_core<0>(sm, A, BT, bias, (which == 0) ? qb : kbf, nullptr, bm, bnn);
}

// output projection: 1D grid 512, XCD-chunked; bf16 A, f32 out
__global__ __launch_bounds__(256, 4) void gemm_out(const u16* __restrict__ A, const u16* __restrict__ BT,
                                                   const float* __restrict__ bias, float* __restrict__ outf){
  __shared__ u16 sm[16384];
  int bi = blockIdx.x;
  int orig = (bi & 7)*64 + (bi >> 3);
  int bm = orig >> 2, bn = orig & 3;
  gemm_core<1>(sm, A, BT, bias, nullptr, outf, bm, bn);
}

// ---------------- banded flash attention, 8 waves x 16 q-rows ----------------
// 1D grid 1024, XCD-chunked (adjacent n co-XCD for K/V L2 reuse)
__global__ __launch_bounds__(512, 4) void attn8(const u16* __restrict__ Qg, const u16* __restrict__ Kg,
                                                const u16* __restrict__ VTg, u16* __restrict__ Og){
  __shared__ u16 lK[128*64];
  __shared__ u16 lVT[64*128];
  __shared__ u16 lP[128*128];
  const int tid = threadIdx.x, lane = tid & 63, w = tid >> 6;
  const int g = lane >> 4, c = lane & 15;
  int bi = blockIdx.x;
  int orig = (bi & 7)*128 + (bi >> 3);
  const int n = orig & 63, h = (orig >> 6) & 7, b = orig >> 9;
  const size_t baseq = ((size_t)(b*8 + h)) << 19;
  const size_t basev = ((size_t)((b*8 + h)*64)) << 13;

  short8 qf0, qf1;
  {
    const u16* qp = Qg + baseq + (size_t)(n*128 + w*16 + c)*64 + g*8;
    qf0 = *(const short8*)qp;
    qf1 = *(const short8*)(qp + 32);
  }

  float m_run = -1e30f, l_run = 0.f;
  f32x4 oacc[4];
  #pragma unroll
  for (int dn = 0; dn < 4; ++dn){ f32x4 z = {0.f,0.f,0.f,0.f}; oacc[dn] = z; }

  const int lo = (n == 0) ? 1 : 0;
  const int hi = (n == 63) ? 1 : 2;

  const int sr = tid >> 2, sq = tid & 3;
  const int vd = tid >> 3, vc = tid & 7;

  short8 kr0, kr1, vr0, vr1;
  {
    int kstart = n*128 + (lo - 1)*128;
    const u16* kp = Kg + baseq + (size_t)(kstart + sr)*64 + sq*16;
    kr0 = *(const short8*)kp; kr1 = *(const short8*)(kp + 8);
    const u16* vp = VTg + basev + ((size_t)vd << 13) + kstart + vc*16;
    vr0 = *(const short8*)vp; vr1 = *(const short8*)(vp + 8);
  }

  const int prow = w*16 + c;
  const float SCL = 0.125f * 1.44269504f;

  for (int kb = lo; kb <= hi; ++kb){
    {
      int byt = sr*128 + ((sq*32) ^ ((sr & 7) << 4));
      *(short8*)((char*)lK + byt) = kr0;
      byt = sr*128 + ((sq*32 + 16) ^ ((sr & 7) << 4));
      *(short8*)((char*)lK + byt) = kr1;
      int byt2 = vd*256 + ((vc*32) ^ ((vd & 7) << 4));
      *(short8*)((char*)lVT + byt2) = vr0;
      byt2 = vd*256 + ((vc*32 + 16) ^ ((vd & 7) << 4));
      *(short8*)((char*)lVT + byt2) = vr1;
    }
    __syncthreads();

    if (kb < hi){
      int kstart = n*128 + kb*128;
      const u16* kp = Kg + baseq + (size_t)(kstart + sr)*64 + sq*16;
      kr0 = *(const short8*)kp; kr1 = *(const short8*)(kp + 8);
      const u16* vp = VTg + basev + ((size_t)vd << 13) + kstart + vc*16;
      vr0 = *(const short8*)vp; vr1 = *(const short8*)(vp + 8);
    }

    f32x4 st[8];
    #pragma unroll
    for (int nt = 0; nt < 8; ++nt){ f32x4 z = {0.f,0.f,0.f,0.f}; st[nt] = z; }
    __builtin_amdgcn_s_setprio(1);
    #pragma unroll
    for (int nt = 0; nt < 8; ++nt){
      int row = nt*16 + c;
      int swz = (row & 7) << 4;
      short8 kf0 = *(const short8*)((char*)lK + row*128 + ((g*16) ^ swz));
      short8 kf1 = *(const short8*)((char*)lK + row*128 + ((64 + g*16) ^ swz));
      st[nt] = MFMA16(kf0, qf0, st[nt]);
      st[nt] = MFMA16(kf1, qf1, st[nt]);
    }
    __builtin_amdgcn_s_setprio(0);

    int koff = (kb - 1)*128 - (w*16 + c);
    float mx = -1e30f;
    #pragma unroll
    for (int nt = 0; nt < 8; ++nt)
      #pragma unroll
      for (int r = 0; r < 4; ++r){
        int rel = koff + nt*16 + 4*g + r;
        float s = (rel >= -128 && rel <= 127) ? st[nt][r] * SCL : -1e30f;
        st[nt][r] = s;
        mx = fmaxf(mx, s);
      }
    mx = fmaxf(mx, __shfl_xor(mx, 16));
    mx = fmaxf(mx, __shfl_xor(mx, 32));
    float mnew = fmaxf(m_run, mx);
    float fac = __builtin_amdgcn_exp2f(m_run - mnew);
    m_run = mnew;
    float rs = 0.f;
    #pragma unroll
    for (int nt = 0; nt < 8; ++nt)
      #pragma unroll
      for (int r = 0; r < 4; ++r){
        float p = __builtin_amdgcn_exp2f(st[nt][r] - mnew);
        st[nt][r] = p; rs += p;
      }
    rs += __shfl_xor(rs, 16);
    rs += __shfl_xor(rs, 32);
    l_run = l_run * fac + rs;
    #pragma unroll
    for (int r = 0; r < 4; ++r){
      float fr = __shfl(fac, g*20 + r);
      #pragma unroll
      for (int dn = 0; dn < 4; ++dn) oacc[dn][r] *= fr;
    }

    #pragma unroll
    for (int nt = 0; nt < 8; ++nt){
      u32 plo, phi;
      asm volatile("v_cvt_pk_bf16_f32 %0, %1, %2" : "=v"(plo) : "v"(st[nt][0]), "v"(st[nt][1]));
      asm volatile("v_cvt_pk_bf16_f32 %0, %1, %2" : "=v"(phi) : "v"(st[nt][2]), "v"(st[nt][3]));
      u32x2 pv = { plo, phi };
      int byt = prow*256 + ((nt*32 + g*8) ^ ((c & 7) << 4));
      *(u32x2*)((char*)lP + byt) = pv;
    }

    __builtin_amdgcn_s_setprio(1);
    #pragma unroll
    for (int kt = 0; kt < 4; ++kt){
      short8 pa = *(const short8*)((char*)lP + prow*256 + ((kt*64 + g*16) ^ ((c & 7) << 4)));
      #pragma unroll
      for (int dn = 0; dn < 4; ++dn){
        int dd = dn*16 + c;
        short8 vb = *(const short8*)((char*)lVT + dd*256 + ((kt*64 + g*16) ^ ((c & 7) << 4)));
        oacc[dn] = MFMA16(pa, vb, oacc[dn]);
      }
    }
    __builtin_amdgcn_s_setprio(0);
    __syncthreads();
  }

  #pragma unroll
  for (int r = 0; r < 4; ++r){
    float li = __shfl(l_run, g*20 + r);
    float inv = 1.0f / li;
    size_t orow = ((size_t)(b*8192 + n*128 + w*16 + 4*g + r))*512 + h*64 + c;
    #pragma unroll
    for (int dn = 0; dn < 4; ++dn)
      Og[orow + dn*16] = f2bf(oacc[dn][r] * inv);
  }
}

extern "C" void kernel_launch(void* const* d_in, const int* in_sizes, int n_in,
                              void* d_out, int out_size, void* d_ws, size_t ws_size,
                              hipStream_t stream) {
  const float* inq  = (const float*)d_in[0];
  const float* inkv = (const float*)d_in[1];
  const float* Wq   = (const float*)d_in[2];
  const float* bq   = (const float*)d_in[3];
  const float* Wk   = (const float*)d_in[4];
  const float* bk   = (const float*)d_in[5];
  const float* Wv   = (const float*)d_in[6];
  const float* bv   = (const float*)d_in[7];
  const float* Wo   = (const float*)d_in[8];
  const float* bo   = (const float*)d_in[9];

  char* ws = (char*)d_ws;
  u16* qb  = (u16*)(ws + 0);                       // 16 MB [B,H,S,D]
  u16* kbf = (u16*)(ws + ((size_t)16 << 20));      // 16 MB [B,H,S,D]
  u16* vT  = (u16*)(ws + ((size_t)32 << 20));      // 16 MB [B*H,D,S]
  u16* ob  = (u16*)(ws + ((size_t)48 << 20));      // 16 MB [B,S,512]
  u16* wT  = (u16*)(ws + ((size_t)64 << 20));      // 2 MB

  wtrans<<<dim3(16,16,4), dim3(32,8), 0, stream>>>(Wq, Wk, Wv, Wo, wT);

  gemm_qkv<<<1536, 256, 0, stream>>>(inq, inkv, wT, bq, bk, bv, qb, kbf, vT);

  attn8<<<1024, 512, 0, stream>>>(qb, kbf, vT, ob);

  gemm_out<<<512, 256, 0, stream>>>(ob, wT + 3*262144, bo, (float*)d_out);
}